// Round 8
// baseline (248.214 us; speedup 1.0000x reference)
//
#include <hip/hip_runtime.h>

#define BATCH 64
#define M_GT  100
#define M1    101
#define NANCH 8732
#define BLOCK 256
#define NPT   2                    // anchors per thread -> dwordx2 stores
#define NTILE (BLOCK * NPT)        // 512
#define NX    18                   // ceil(8732/512)
#define NBLK  (NX * BATCH)         // 1152 blocks = 4608 waves
#define NXCD  8
#define GR    16                   // rows per compute/store phase
#define NPH   (MBULK / GR)         // 6 bulk phases
#define MBULK ((M1 / GR) * GR)     // 96
#define MTAIL (M1 - MBULK)         // 5

// Journal:
//  R0: NPT=4, 576 blocks                    -> 245.7 (baseline)
//  R1: NPT=2, depth-8 groups, 1152 blocks   -> 244.4 neutral
//  R2: nontemporal stores                   -> 279.3 REGRESSION (L2 merge load-bearing)
//  R3: XCD-grouping swizzle                 -> 240.4 (+4, best)
//  R4: role-split contiguous writer         -> 265.8 REGRESSION (CONFOUNDED: doubled VALU)
//  R5: double compute+store pass            -> 264.8 (marginal pass 24.4 µs; output L3-fits)
//  R6: diagnostic, kernel counters:         VALUBusy 83%, FETCH ~1 MB, WRITE 233 MB;
//      single-pass ~67 µs = VALU ~25-30 + eviction-drain ~42 (at 5.5 TB/s), SERIALIZED.
//  R7: GR=16 phase split                    -> 240.8 NEUTRAL. Structure still forces
//      the vmcnt reuse-wait immediately after each burst (compute overwrites res next).
//  R8 (this): store software-pipeline. Double-buffered resA/resB, order
//      store(p,A); compute(p+1,B); store(p+1,B); compute(p+2,A) -> the
//      reuse-wait lands ONE COMPUTE PHASE after issue (counted vmcnt(16),
//      32 outstanding), so every wave covers its in-flight burst with VALU.
__global__ __launch_bounds__(BLOCK) void encode_fused(
    const float* __restrict__ labels,   // [B, M, 5]
    const float* __restrict__ dboxes,   // [N, 4]
    float* __restrict__ out_labeled,    // [B, N, 5]
    float* __restrict__ out_ious)       // [B, M1, N]
{
    __shared__ float4 s_box[M1];
    __shared__ float  s_ar[M1], s_cls[M1];

    const int tid = threadIdx.x;
    // XCD-grouping swizzle (R3): all NX chunks of each b on one XCD.
    const int x  = blockIdx.x % NXCD;
    const int j  = blockIdx.x / NXCD;
    const int b  = x * (BATCH / NXCD) + j / NX;
    const int nb = j % NX;

    if (tid < M1) {
        float x1 = 0.f, y1 = 0.f, x2 = 0.f, y2 = 0.f, cls = 0.f;
        float ar = __builtin_inff();   // pad/invalid -> iou = inter*rcp(inf) = +0
        if (tid >= 1) {
            const float* row = labels + ((size_t)b * M_GT + (tid - 1)) * 5;
            x1 = row[0]; y1 = row[1]; x2 = row[2]; y2 = row[3]; cls = row[4];
            if (cls != 0.0f) ar = (x2 - x1) * (y2 - y1);
        }
        s_box[tid] = make_float4(x1, y1, x2, y2);
        s_ar[tid] = ar; s_cls[tid] = cls;
    }
    __syncthreads();

    const int n0 = nb * NTILE + tid * NPT;
    if (n0 >= NANCH) return;

    float ax1[NPT], ay1[NPT], ax2[NPT], ay2[NPT], aa[NPT];
    #pragma unroll
    for (int i = 0; i < NPT; ++i) {
        const float4 d = *reinterpret_cast<const float4*>(dboxes + (size_t)(n0 + i) * 4);
        ax1[i] = d.x; ay1[i] = d.y; ax2[i] = d.z; ay2[i] = d.w;
        aa[i]  = (d.z - d.x) * (d.w - d.y);
    }

    float* const irow = out_ious + (size_t)b * M1 * NANCH + n0;

    // best=-1: pad rows give iou=+0; strict > = numpy first-occurrence argmax.
    float best[NPT]; int besti[NPT];
    #pragma unroll
    for (int i = 0; i < NPT; ++i) { best[i] = -1.0f; besti[i] = 0; }

    // Compute GR rows starting at mg into res[] (static r indexing, rule #20).
    auto compute_phase = [&](int mg, float2* res) {
        #pragma unroll
        for (int r = 0; r < GR; ++r) {
            const int m = mg + r;
            const float4 g = s_box[m];      // ds_read_b128 broadcast
            const float ga = s_ar[m];       // ds_read_b32 broadcast
            float iou[NPT];
            #pragma unroll
            for (int i = 0; i < NPT; ++i) {
                const float ix1 = fmaxf(g.x, ax1[i]), iy1 = fmaxf(g.y, ay1[i]);
                const float ix2 = fminf(g.z, ax2[i]), iy2 = fminf(g.w, ay2[i]);
                const float iw = fmaxf(ix2 - ix1, 0.0f), ih = fmaxf(iy2 - iy1, 0.0f);
                const float inter = iw * ih;
                iou[i] = inter * __builtin_amdgcn_rcpf(ga + aa[i] - inter);
                if (iou[i] > best[i]) { best[i] = iou[i]; besti[i] = m; }
            }
            res[r].x = iou[0]; res[r].y = iou[1];
        }
    };
    auto store_phase = [&](int mg, const float2* res) {
        #pragma unroll
        for (int r = 0; r < GR; ++r)
            *reinterpret_cast<float2*>(irow + (size_t)(mg + r) * NANCH) = res[r];
    };

    // 2-deep pipelined schedule over 6 bulk phases:
    //   compute(0,A)
    //   store(0,A) compute(1,B) | store(1,B) compute(2,A) | ... | store(5,B)
    // Reuse-waits become counted vmcnt(16) one compute phase after issue.
    float2 resA[GR], resB[GR];
    compute_phase(0 * GR, resA);
    store_phase  (0 * GR, resA);  compute_phase(1 * GR, resB);
    store_phase  (1 * GR, resB);  compute_phase(2 * GR, resA);
    store_phase  (2 * GR, resA);  compute_phase(3 * GR, resB);
    store_phase  (3 * GR, resB);  compute_phase(4 * GR, resA);
    store_phase  (4 * GR, resA);  compute_phase(5 * GR, resB);
    store_phase  (5 * GR, resB);

    // Tail: 5 rows (m = 96..100).
    {
        float2 resT[MTAIL];
        #pragma unroll
        for (int r = 0; r < MTAIL; ++r) {
            const int m = MBULK + r;
            const float4 g = s_box[m];
            const float ga = s_ar[m];
            float iou[NPT];
            #pragma unroll
            for (int i = 0; i < NPT; ++i) {
                const float ix1 = fmaxf(g.x, ax1[i]), iy1 = fmaxf(g.y, ay1[i]);
                const float ix2 = fminf(g.z, ax2[i]), iy2 = fminf(g.w, ay2[i]);
                const float iw = fmaxf(ix2 - ix1, 0.0f), ih = fmaxf(iy2 - iy1, 0.0f);
                const float inter = iw * ih;
                iou[i] = inter * __builtin_amdgcn_rcpf(ga + aa[i] - inter);
                if (iou[i] > best[i]) { best[i] = iou[i]; besti[i] = m; }
            }
            resT[r].x = iou[0]; resT[r].y = iou[1];
        }
        #pragma unroll
        for (int r = 0; r < MTAIL; ++r)
            *reinterpret_cast<float2*>(irow + (size_t)(MBULK + r) * NANCH) = resT[r];
    }

    // Epilogue
    float lw[NPT * 5];
    #pragma unroll
    for (int i = 0; i < NPT; ++i) {
        const int idx = (best[i] > 0.5f) ? besti[i] : 0;
        float ox = 0.f, oy = 0.f, ow = 0.f, oh = 0.f, pcls = 0.f;
        if (idx != 0) {   // iou>0.5 winner is always a valid (cls!=0) row
            const float4 t = s_box[idx];
            const float aw = ax2[i] - ax1[i], ah = ay2[i] - ay1[i];
            ox = (0.5f * (t.x + t.z) - 0.5f * (ax1[i] + ax2[i])) / aw;
            oy = (0.5f * (t.y + t.w) - 0.5f * (ay1[i] + ay2[i])) / ah;
            ow = __logf((t.z - t.x) / aw);
            oh = __logf((t.w - t.y) / ah);
            pcls = s_cls[idx];
        }
        lw[i * 5 + 0] = ox; lw[i * 5 + 1] = oy; lw[i * 5 + 2] = ow;
        lw[i * 5 + 3] = oh; lw[i * 5 + 4] = pcls;
    }
    // 10 contiguous floats = 40B, 8B-aligned (n0 even) -> 5 dwordx2 stores
    float* lrow = out_labeled + ((size_t)b * NANCH + n0) * 5;
    #pragma unroll
    for (int k = 0; k < 5; ++k) {
        float2 v; v.x = lw[k * 2]; v.y = lw[k * 2 + 1];
        *reinterpret_cast<float2*>(lrow + k * 2) = v;
    }
}

extern "C" void kernel_launch(void* const* d_in, const int* in_sizes, int n_in,
                              void* d_out, int out_size, void* d_ws, size_t ws_size,
                              hipStream_t stream) {
    const float* labels = (const float*)d_in[0];
    const float* dboxes = (const float*)d_in[1];
    float* out_labeled = (float*)d_out;
    float* out_ious    = out_labeled + (size_t)BATCH * NANCH * 5;

    encode_fused<<<dim3(NBLK), dim3(BLOCK), 0, stream>>>(labels, dboxes, out_labeled, out_ious);
}

// Round 9
// 247.184 us; speedup vs baseline: 1.0042x; 1.0042x over previous
//
#include <hip/hip_runtime.h>

#define BATCH 64
#define M_GT  100
#define M1    101
#define NANCH 8732
#define BLOCK 256
#define NPT   2                    // anchors per thread -> dwordx2 stores
#define NTILE (BLOCK * NPT)        // 512
#define NX    18                   // ceil(8732/512)
#define NBLK  (NX * BATCH)         // 1152 blocks = 4608 waves
#define NXCD  8
#define GR    16                   // rows per compute/store phase
#define MBULK ((M1 / GR) * GR)     // 96
#define MTAIL (M1 - MBULK)         // 5

// Journal:
//  R0: NPT=4, 576 blocks                  -> 245.7 baseline
//  R1: depth-8 bursts, 2x waves           -> 244.4 neutral (depth/count invariant)
//  R2: nontemporal stores                 -> 279.3 REGRESSION (L2 merge load-bearing)
//  R3: XCD-grouping swizzle               -> 240.4 best
//  R4: role-split writer                  -> 265.8 (confounded +30µs VALU; memory-neutral)
//  R5: 2x compute+store pass              -> 264.8 (+24.4/pass)
//  R6: +3 compute-only passes             -> kernel row: VALUBusy 83%, FETCH 1MB, WRITE 233MB.
//      Marginal compute pass 17.6 µs wall but ~30 µs VALU content => stalls ARE
//      coverable by other waves' VALU. Single pass ~92 µs = 30 VALU + 60 stall.
//  R7: GR=16 phase split                  -> 240.8 neutral
//  R8: within-wave store pipeline (lag-1) -> 248.2 (ack-wait theory refuted 2x w/ R1)
//  R9 (this): CROSS-WAVE schedule mix. All prior versions run every wave through
//      an identical stream launched in lockstep -> backpressure parks ALL waves
//      at stores simultaneously. Now half the waves run the store-now schedule,
//      half run the lag-1 schedule (wave-uniform branch): store bursts of the two
//      classes are offset half a phase, so each SIMD always holds a wave with
//      issueable VALU. Compute order 0..100 preserved in both arms (argmax
//      tie-break semantics identical).
__global__ __launch_bounds__(BLOCK) void encode_fused(
    const float* __restrict__ labels,   // [B, M, 5]
    const float* __restrict__ dboxes,   // [N, 4]
    float* __restrict__ out_labeled,    // [B, N, 5]
    float* __restrict__ out_ious)       // [B, M1, N]
{
    __shared__ float4 s_box[M1];
    __shared__ float  s_ar[M1], s_cls[M1];

    const int tid = threadIdx.x;
    // XCD-grouping swizzle (R3): all NX chunks of each b on one XCD.
    const int x  = blockIdx.x % NXCD;
    const int j  = blockIdx.x / NXCD;
    const int b  = x * (BATCH / NXCD) + j / NX;
    const int nb = j % NX;

    if (tid < M1) {
        float x1 = 0.f, y1 = 0.f, x2 = 0.f, y2 = 0.f, cls = 0.f;
        float ar = __builtin_inff();   // pad/invalid -> iou = inter*rcp(inf) = +0
        if (tid >= 1) {
            const float* row = labels + ((size_t)b * M_GT + (tid - 1)) * 5;
            x1 = row[0]; y1 = row[1]; x2 = row[2]; y2 = row[3]; cls = row[4];
            if (cls != 0.0f) ar = (x2 - x1) * (y2 - y1);
        }
        s_box[tid] = make_float4(x1, y1, x2, y2);
        s_ar[tid] = ar; s_cls[tid] = cls;
    }
    __syncthreads();

    const int n0 = nb * NTILE + tid * NPT;
    if (n0 >= NANCH) return;

    float ax1[NPT], ay1[NPT], ax2[NPT], ay2[NPT], aa[NPT];
    #pragma unroll
    for (int i = 0; i < NPT; ++i) {
        const float4 d = *reinterpret_cast<const float4*>(dboxes + (size_t)(n0 + i) * 4);
        ax1[i] = d.x; ay1[i] = d.y; ax2[i] = d.z; ay2[i] = d.w;
        aa[i]  = (d.z - d.x) * (d.w - d.y);
    }

    float* const irow = out_ious + (size_t)b * M1 * NANCH + n0;

    // best=-1: pad rows give iou=+0; strict > = numpy first-occurrence argmax.
    float best[NPT]; int besti[NPT];
    #pragma unroll
    for (int i = 0; i < NPT; ++i) { best[i] = -1.0f; besti[i] = 0; }

    // Compute GR rows starting at mg into res[] (static indexing, rule #20).
    auto compute_phase = [&](int mg, float2* res) {
        #pragma unroll
        for (int r = 0; r < GR; ++r) {
            const int m = mg + r;
            const float4 g = s_box[m];      // ds_read_b128 broadcast
            const float ga = s_ar[m];       // ds_read_b32 broadcast
            float iou[NPT];
            #pragma unroll
            for (int i = 0; i < NPT; ++i) {
                const float ix1 = fmaxf(g.x, ax1[i]), iy1 = fmaxf(g.y, ay1[i]);
                const float ix2 = fminf(g.z, ax2[i]), iy2 = fminf(g.w, ay2[i]);
                const float iw = fmaxf(ix2 - ix1, 0.0f), ih = fmaxf(iy2 - iy1, 0.0f);
                const float inter = iw * ih;
                iou[i] = inter * __builtin_amdgcn_rcpf(ga + aa[i] - inter);
                if (iou[i] > best[i]) { best[i] = iou[i]; besti[i] = m; }
            }
            res[r].x = iou[0]; res[r].y = iou[1];
        }
    };
    auto store_phase = [&](int mg, const float2* res) {
        #pragma unroll
        for (int r = 0; r < GR; ++r)
            *reinterpret_cast<float2*>(irow + (size_t)(mg + r) * NANCH) = res[r];
    };

    // Wave-uniform schedule class: half store-now (R7), half lag-1 (R8).
    const bool lag = (((tid >> 6) ^ blockIdx.x) & 1) != 0;

    if (!lag) {
        // Store-now schedule.
        float2 res[GR];
        #pragma unroll 1
        for (int p = 0; p < MBULK / GR; ++p) {
            compute_phase(p * GR, res);
            store_phase(p * GR, res);
        }
    } else {
        // Lag-1 schedule: store(p) issued after compute(p+1).
        float2 resA[GR], resB[GR];
        compute_phase(0 * GR, resA);
        compute_phase(1 * GR, resB);  store_phase(0 * GR, resA);
        compute_phase(2 * GR, resA);  store_phase(1 * GR, resB);
        compute_phase(3 * GR, resB);  store_phase(2 * GR, resA);
        compute_phase(4 * GR, resA);  store_phase(3 * GR, resB);
        compute_phase(5 * GR, resB);  store_phase(4 * GR, resA);
        store_phase(5 * GR, resB);
    }

    // Tail: 5 rows (m = 96..100), both classes.
    {
        float2 resT[MTAIL];
        #pragma unroll
        for (int r = 0; r < MTAIL; ++r) {
            const int m = MBULK + r;
            const float4 g = s_box[m];
            const float ga = s_ar[m];
            float iou[NPT];
            #pragma unroll
            for (int i = 0; i < NPT; ++i) {
                const float ix1 = fmaxf(g.x, ax1[i]), iy1 = fmaxf(g.y, ay1[i]);
                const float ix2 = fminf(g.z, ax2[i]), iy2 = fminf(g.w, ay2[i]);
                const float iw = fmaxf(ix2 - ix1, 0.0f), ih = fmaxf(iy2 - iy1, 0.0f);
                const float inter = iw * ih;
                iou[i] = inter * __builtin_amdgcn_rcpf(ga + aa[i] - inter);
                if (iou[i] > best[i]) { best[i] = iou[i]; besti[i] = m; }
            }
            resT[r].x = iou[0]; resT[r].y = iou[1];
        }
        #pragma unroll
        for (int r = 0; r < MTAIL; ++r)
            *reinterpret_cast<float2*>(irow + (size_t)(MBULK + r) * NANCH) = resT[r];
    }

    // Epilogue
    float lw[NPT * 5];
    #pragma unroll
    for (int i = 0; i < NPT; ++i) {
        const int idx = (best[i] > 0.5f) ? besti[i] : 0;
        float ox = 0.f, oy = 0.f, ow = 0.f, oh = 0.f, pcls = 0.f;
        if (idx != 0) {   // iou>0.5 winner is always a valid (cls!=0) row
            const float4 t = s_box[idx];
            const float aw = ax2[i] - ax1[i], ah = ay2[i] - ay1[i];
            ox = (0.5f * (t.x + t.z) - 0.5f * (ax1[i] + ax2[i])) / aw;
            oy = (0.5f * (t.y + t.w) - 0.5f * (ay1[i] + ay2[i])) / ah;
            ow = __logf((t.z - t.x) / aw);
            oh = __logf((t.w - t.y) / ah);
            pcls = s_cls[idx];
        }
        lw[i * 5 + 0] = ox; lw[i * 5 + 1] = oy; lw[i * 5 + 2] = ow;
        lw[i * 5 + 3] = oh; lw[i * 5 + 4] = pcls;
    }
    // 10 contiguous floats = 40B, 8B-aligned (n0 even) -> 5 dwordx2 stores
    float* lrow = out_labeled + ((size_t)b * NANCH + n0) * 5;
    #pragma unroll
    for (int k = 0; k < 5; ++k) {
        float2 v; v.x = lw[k * 2]; v.y = lw[k * 2 + 1];
        *reinterpret_cast<float2*>(lrow + k * 2) = v;
    }
}

extern "C" void kernel_launch(void* const* d_in, const int* in_sizes, int n_in,
                              void* d_out, int out_size, void* d_ws, size_t ws_size,
                              hipStream_t stream) {
    const float* labels = (const float*)d_in[0];
    const float* dboxes = (const float*)d_in[1];
    float* out_labeled = (float*)d_out;
    float* out_ious    = out_labeled + (size_t)BATCH * NANCH * 5;

    encode_fused<<<dim3(NBLK), dim3(BLOCK), 0, stream>>>(labels, dboxes, out_labeled, out_ious);
}

// Round 10
// 241.038 us; speedup vs baseline: 1.0298x; 1.0255x over previous
//
#include <hip/hip_runtime.h>

#define BATCH 64
#define M_GT  100
#define M1    101
#define NANCH 8732
#define BLOCK 256
#define NPT   2                    // anchors per thread -> dwordx2 stores
#define NTILE (BLOCK * NPT)        // 512
#define NX    18                   // ceil(8732/512)
#define NBLK  (NX * BATCH)         // 1152 blocks = 4608 waves
#define NXCD  8
#define GROUP 8                    // rows per store burst
#define MBULK ((M1 / GROUP) * GROUP)   // 96
#define MTAIL (M1 - MBULK)             // 5

// FINAL (R10) = R3 restored, session best 240.4 µs.
//
// Session ledger (dur_us; kernel portion ~= dur - 141 fill - 31 harness):
//  R0 baseline NPT=4, 576 blk        245.7
//  R1 depth-8 bursts, 2x waves       244.4  neutral
//  R2 nontemporal stores             279.3  REGRESSION (L2 write-merge load-bearing)
//  R3 XCD-grouping swizzle           240.4  BEST (kept here)
//  R4 role-split writer              265.8  (confounded: doubled VALU; memory-neutral)
//  R5 2x compute+store pass          264.8  marginal pass 24.4 µs
//  R6 +3 compute-only passes         317.7  -> kernel counters: VALUBusy 83%,
//     FETCH 1 MB, WRITE 233 MB (= output, no amplification), conflicts ~0.
//     Single-pass kernel ~67 µs = ~30 µs VALU + ~37 µs stall.
//  R7 GR=16 phase split              240.8  neutral
//  R8 lag-1 store pipeline           248.2  (ack-wait refuted)
//  R9 cross-wave schedule mix        247.2  (phase-diversity refuted)
//
// Ceiling: dur = 141.4 (harness poison fill, fixed) + ~31 (harness tiny
// dispatches, fixed) + ~67 kernel. Store depth/width/wave-count/contiguity/
// nt/XCD-map/phase-split/pipelining/cross-wave-mix all neutral-or-worse;
// VALU floor ~30 µs at measured 83% pipe busy. Remaining ~30 µs gap is not
// source-addressable per the ten falsified mechanisms above.
__global__ __launch_bounds__(BLOCK) void encode_fused(
    const float* __restrict__ labels,   // [B, M, 5]
    const float* __restrict__ dboxes,   // [N, 4]
    float* __restrict__ out_labeled,    // [B, N, 5]
    float* __restrict__ out_ious)       // [B, M1, N]
{
    __shared__ float4 s_box[M1];        // {x1,y1,x2,y2}
    __shared__ float  s_ar[M1], s_cls[M1];

    const int tid = threadIdx.x;
    // XCD-grouping swizzle (R3): all NX chunks of each b on one XCD,
    // launched back-to-back (dispatcher maps blockIdx%8 -> XCD).
    const int x  = blockIdx.x % NXCD;
    const int j  = blockIdx.x / NXCD;
    const int b  = x * (BATCH / NXCD) + j / NX;
    const int nb = j % NX;

    if (tid < M1) {
        float x1 = 0.f, y1 = 0.f, x2 = 0.f, y2 = 0.f, cls = 0.f;
        float ar = __builtin_inff();   // pad/invalid -> iou = inter*rcp(inf) = +0
        if (tid >= 1) {
            const float* row = labels + ((size_t)b * M_GT + (tid - 1)) * 5;
            x1 = row[0]; y1 = row[1]; x2 = row[2]; y2 = row[3]; cls = row[4];
            if (cls != 0.0f) ar = (x2 - x1) * (y2 - y1);
        }
        s_box[tid] = make_float4(x1, y1, x2, y2);
        s_ar[tid] = ar; s_cls[tid] = cls;
    }
    __syncthreads();

    const int n0 = nb * NTILE + tid * NPT;
    if (n0 >= NANCH) return;           // NANCH % 2 == 0 -> whole pair in/out

    float ax1[NPT], ay1[NPT], ax2[NPT], ay2[NPT], aa[NPT];
    #pragma unroll
    for (int i = 0; i < NPT; ++i) {
        const float4 d = *reinterpret_cast<const float4*>(dboxes + (size_t)(n0 + i) * 4);
        ax1[i] = d.x; ay1[i] = d.y; ax2[i] = d.z; ay2[i] = d.w;
        aa[i]  = (d.z - d.x) * (d.w - d.y);
    }

    float* const irow = out_ious + (size_t)b * M1 * NANCH + n0;

    // best=-1: pad rows give iou=+0; strict > = numpy first-occurrence argmax.
    float best[NPT]; int besti[NPT];
    #pragma unroll
    for (int i = 0; i < NPT; ++i) { best[i] = -1.0f; besti[i] = 0; }

    // One row: compute NPT ious, update running argmax, store 8B.
    auto row_body = [&](int m) {
        const float4 g = s_box[m];      // ds_read_b128 broadcast
        const float ga = s_ar[m];       // ds_read_b32 broadcast
        float iou[NPT];
        #pragma unroll
        for (int i = 0; i < NPT; ++i) {
            const float ix1 = fmaxf(g.x, ax1[i]), iy1 = fmaxf(g.y, ay1[i]);
            const float ix2 = fminf(g.z, ax2[i]), iy2 = fminf(g.w, ay2[i]);
            const float iw = fmaxf(ix2 - ix1, 0.0f), ih = fmaxf(iy2 - iy1, 0.0f);
            const float inter = iw * ih;
            iou[i] = inter * __builtin_amdgcn_rcpf(ga + aa[i] - inter);  // validated
            if (iou[i] > best[i]) { best[i] = iou[i]; besti[i] = m; }
        }
        float2 w; w.x = iou[0]; w.y = iou[1];
        *reinterpret_cast<float2*>(irow + (size_t)m * NANCH) = w;
    };

    for (int mg = 0; mg < MBULK; mg += GROUP) {
        #pragma unroll
        for (int r = 0; r < GROUP; ++r) row_body(mg + r);
    }
    #pragma unroll
    for (int r = 0; r < MTAIL; ++r) row_body(MBULK + r);

    // Epilogue
    float lw[NPT * 5];
    #pragma unroll
    for (int i = 0; i < NPT; ++i) {
        const int idx = (best[i] > 0.5f) ? besti[i] : 0;
        float ox = 0.f, oy = 0.f, ow = 0.f, oh = 0.f, pcls = 0.f;
        if (idx != 0) {   // iou>0.5 winner is always a valid (cls!=0) row
            const float4 t = s_box[idx];
            const float aw = ax2[i] - ax1[i], ah = ay2[i] - ay1[i];
            ox = (0.5f * (t.x + t.z) - 0.5f * (ax1[i] + ax2[i])) / aw;
            oy = (0.5f * (t.y + t.w) - 0.5f * (ay1[i] + ay2[i])) / ah;
            ow = __logf((t.z - t.x) / aw);
            oh = __logf((t.w - t.y) / ah);
            pcls = s_cls[idx];
        }
        lw[i * 5 + 0] = ox; lw[i * 5 + 1] = oy; lw[i * 5 + 2] = ow;
        lw[i * 5 + 3] = oh; lw[i * 5 + 4] = pcls;
    }
    // 10 contiguous floats = 40B, 8B-aligned (n0 even) -> 5 dwordx2 stores
    float* lrow = out_labeled + ((size_t)b * NANCH + n0) * 5;
    #pragma unroll
    for (int k = 0; k < 5; ++k) {
        float2 v; v.x = lw[k * 2]; v.y = lw[k * 2 + 1];
        *reinterpret_cast<float2*>(lrow + k * 2) = v;
    }
}

extern "C" void kernel_launch(void* const* d_in, const int* in_sizes, int n_in,
                              void* d_out, int out_size, void* d_ws, size_t ws_size,
                              hipStream_t stream) {
    const float* labels = (const float*)d_in[0];
    const float* dboxes = (const float*)d_in[1];
    float* out_labeled = (float*)d_out;
    float* out_ious    = out_labeled + (size_t)BATCH * NANCH * 5;

    encode_fused<<<dim3(NBLK), dim3(BLOCK), 0, stream>>>(labels, dboxes, out_labeled, out_ious);
}